// Round 2
// baseline (1072.056 us; speedup 1.0000x reference)
//
#include <hip/hip_runtime.h>

#define D_MODEL 2048
#define NHEADS 16
#define HDIM 128
#define HIDDEN_ 5461
#define HP 5504
#define BATCH 2
#define SEQ 2048
#define MTOK 4096

typedef unsigned short u16;
typedef __attribute__((ext_vector_type(8))) short bf16x8;
typedef __attribute__((ext_vector_type(4))) float f32x4;

__device__ __forceinline__ u16 f2b(float f) {
  union { float f; unsigned u; } v; v.f = f;
  return (u16)((v.u + 0x7FFFu + ((v.u >> 16) & 1u)) >> 16);
}
__device__ __forceinline__ float b2f(u16 u) {
  union { unsigned u; float f; } v; v.u = ((unsigned)u) << 16;
  return v.f;
}
__device__ __forceinline__ void gload16(const void* g, void* l) {
  __builtin_amdgcn_global_load_lds(
      (const __attribute__((address_space(1))) unsigned int*)g,
      (__attribute__((address_space(3))) unsigned int*)l, 16, 0, 0);
}

// ---------------- conversions ----------------
__global__ __launch_bounds__(256) void k_conv8(const float* __restrict__ src,
                                               u16* __restrict__ dst, int n8) {
  int stride = gridDim.x * 256;
  for (int i = blockIdx.x * 256 + threadIdx.x; i < n8; i += stride) {
    const float4* s = (const float4*)src + (size_t)i * 2;
    float4 a = s[0], b = s[1];
    bf16x8 o;
    o[0] = f2b(a.x); o[1] = f2b(a.y); o[2] = f2b(a.z); o[3] = f2b(a.w);
    o[4] = f2b(b.x); o[5] = f2b(b.y); o[6] = f2b(b.z); o[7] = f2b(b.w);
    ((bf16x8*)dst)[i] = o;
  }
}

__global__ __launch_bounds__(256) void k_convpad(const float* __restrict__ src,
                                                 u16* __restrict__ dst,
                                                 int srows, int scols, int drows, int dcols) {
  size_t n = (size_t)drows * dcols;
  size_t stride = (size_t)gridDim.x * 256;
  for (size_t i = blockIdx.x * 256 + threadIdx.x; i < n; i += stride) {
    int r = (int)(i / dcols), c = (int)(i % dcols);
    float v = (r < srows && c < scols) ? src[(size_t)r * scols + c] : 0.f;
    dst[i] = f2b(v);
  }
}

// ---------------- rmsnorm (fp32 in, bf16 out) ----------------
__global__ __launch_bounds__(256) void k_rmsnorm(const float* __restrict__ X,
                                                 const float* __restrict__ G,
                                                 u16* __restrict__ Out) {
  int row = blockIdx.x;
  int tid = threadIdx.x;
  const float4* x4 = (const float4*)(X + (size_t)row * D_MODEL);
  float4 a = x4[tid * 2], b = x4[tid * 2 + 1];
  float ss = a.x * a.x + a.y * a.y + a.z * a.z + a.w * a.w +
             b.x * b.x + b.y * b.y + b.z * b.z + b.w * b.w;
#pragma unroll
  for (int off = 1; off < 64; off <<= 1) ss += __shfl_xor(ss, off);
  __shared__ float part[4];
  if ((tid & 63) == 0) part[tid >> 6] = ss;
  __syncthreads();
  float rstd = rsqrtf((part[0] + part[1] + part[2] + part[3]) * (1.0f / D_MODEL) + 1e-6f);
  const float4* g4 = (const float4*)G;
  float4 ga = g4[tid * 2], gb = g4[tid * 2 + 1];
  bf16x8 o;
  o[0] = f2b(a.x * rstd * ga.x); o[1] = f2b(a.y * rstd * ga.y);
  o[2] = f2b(a.z * rstd * ga.z); o[3] = f2b(a.w * rstd * ga.w);
  o[4] = f2b(b.x * rstd * gb.x); o[5] = f2b(b.y * rstd * gb.y);
  o[6] = f2b(b.z * rstd * gb.z); o[7] = f2b(b.w * rstd * gb.w);
  *((bf16x8*)(Out + (size_t)row * D_MODEL) + tid) = o;
}

// ---------------- GEMM: C[M,N] = A[M,K] * Bw[N,K]^T (bf16 in, f32 acc) ----------------
// EPI 0: bf16 store
// EPI 1: f32 out = acc + bias[col] + res[idx]
// EPI 2: f32 out = acc + res[idx]   (res may alias Out; 1:1 idx, safe)
// EPI 3: bf16 out = silu(aux[idx]) * acc, written to aux (in-place)
template <int EPI>
__global__ __launch_bounds__(256) void k_gemm(const u16* __restrict__ A,
                                              const u16* __restrict__ Bw,
                                              void* __restrict__ Out,
                                              const float* __restrict__ bias,
                                              const float* __restrict__ res,
                                              const u16* __restrict__ aux,
                                              int M, int N, int K) {
  __shared__ u16 At[128 * 32];
  __shared__ u16 Bt[128 * 32];
  const int tid = threadIdx.x;
  const int w = tid >> 6, lane = tid & 63;
  const int lo = lane & 15, hi = lane >> 4;
  const int m0 = blockIdx.y * 128, n0 = blockIdx.x * 128;
  const int wr = w >> 1, wc = w & 1;
  f32x4 acc[4][4];
#pragma unroll
  for (int i = 0; i < 4; i++)
#pragma unroll
    for (int j = 0; j < 4; j++) acc[i][j] = (f32x4){0.f, 0.f, 0.f, 0.f};

  const int srow = lane >> 2;                      // row within 16-row chunk
  const int scol = ((lane & 3) ^ (srow & 3)) * 8;  // swizzled source slot (elems)

  for (int k0 = 0; k0 < K; k0 += 32) {
#pragma unroll
    for (int t = 0; t < 2; t++) {
      int c = w + t * 4;  // chunk 0..7, 16 rows each
      const u16* ga = A + (size_t)(m0 + c * 16 + srow) * K + k0 + scol;
      gload16(ga, (char*)At + c * 1024);
      const u16* gb = Bw + (size_t)(n0 + c * 16 + srow) * K + k0 + scol;
      gload16(gb, (char*)Bt + c * 1024);
    }
    __syncthreads();
    bf16x8 af[4], bw[4];
#pragma unroll
    for (int i = 0; i < 4; i++) {
      int r = wr * 64 + i * 16 + lo;
      af[i] = *(const bf16x8*)(At + r * 32 + ((hi ^ (r & 3)) * 8));
    }
#pragma unroll
    for (int j = 0; j < 4; j++) {
      int r = wc * 64 + j * 16 + lo;
      bw[j] = *(const bf16x8*)(Bt + r * 32 + ((hi ^ (r & 3)) * 8));
    }
#pragma unroll
    for (int i = 0; i < 4; i++)
#pragma unroll
      for (int j = 0; j < 4; j++)
        acc[i][j] = __builtin_amdgcn_mfma_f32_16x16x32_bf16(af[i], bw[j], acc[i][j], 0, 0, 0);
    __syncthreads();
  }
#pragma unroll
  for (int i = 0; i < 4; i++) {
#pragma unroll
    for (int j = 0; j < 4; j++) {
      int col = n0 + wc * 64 + j * 16 + lo;
#pragma unroll
      for (int r = 0; r < 4; r++) {
        int row = m0 + wr * 64 + i * 16 + hi * 4 + r;
        size_t idx = (size_t)row * N + col;
        float v = acc[i][j][r];
        if (EPI == 0) {
          ((u16*)Out)[idx] = f2b(v);
        } else if (EPI == 1) {
          ((float*)Out)[idx] = v + bias[col] + res[idx];
        } else if (EPI == 2) {
          ((float*)Out)[idx] = v + res[idx];
        } else {
          float v1 = b2f(aux[idx]);
          float sig = 1.f / (1.f + __expf(-v1));
          ((u16*)Out)[idx] = f2b(v1 * sig * v);
        }
      }
    }
  }
}

// ---------------- RoPE (in-place on bf16 q,k) ----------------
__global__ __launch_bounds__(256) void k_rope(u16* __restrict__ Qb, u16* __restrict__ Kb,
                                              const float* __restrict__ F) {
  int n = MTOK * (D_MODEL / 2);
  int stride = gridDim.x * 256;
  for (int t = blockIdx.x * 256 + threadIdx.x; t < n; t += stride) {
    int i = t & 63;
    int rest = t >> 6;
    int hh = rest & 15;
    int tok = rest >> 4;
    int s = tok & (SEQ - 1);
    float4 f = ((const float4*)F)[s * 64 + i];  // f[j=0,k=0],f[0,1],f[1,0],f[1,1]
    size_t off = (size_t)tok * D_MODEL + hh * HDIM + i * 2;
    float x0 = b2f(Qb[off]), x1 = b2f(Qb[off + 1]);
    Qb[off] = f2b(x0 * f.x + x1 * f.y);
    Qb[off + 1] = f2b(x0 * f.z + x1 * f.w);
    x0 = b2f(Kb[off]); x1 = b2f(Kb[off + 1]);
    Kb[off] = f2b(x0 * f.x + x1 * f.y);
    Kb[off + 1] = f2b(x0 * f.z + x1 * f.w);
  }
}

// ---------------- flash attention (non-causal), 64 q-rows/block ----------------
__global__ __launch_bounds__(256) void k_flash(const u16* __restrict__ Q,
                                               const u16* __restrict__ Kb,
                                               const u16* __restrict__ Vb,
                                               u16* __restrict__ O) {
  __shared__ u16 Kt[32 * 128];     // [k][d], XOR-swizzled (slot ^= row&7)
  __shared__ u16 Vt[128 * 32];     // [d][k], XOR-swizzled
  __shared__ u16 Pl[4][16 * 40];   // per-wave P, padded stride
  const int tid = threadIdx.x;
  const int w = tid >> 6, lane = tid & 63;
  const int lo = lane & 15, hi = lane >> 4;
  const int qt = blockIdx.x, bh = blockIdx.y;
  const int b = bh >> 4, h = bh & 15;
  const size_t qrow0 = (size_t)b * SEQ + qt * 64 + w * 16;

  bf16x8 aQ[4];
#pragma unroll
  for (int kb = 0; kb < 4; kb++)
    aQ[kb] = *(const bf16x8*)(Q + (qrow0 + lo) * D_MODEL + h * HDIM + kb * 32 + hi * 8);

  float m_s[4], l_s[4];
  f32x4 oacc[8];
#pragma unroll
  for (int r = 0; r < 4; r++) { m_s[r] = -3.0e38f; l_s[r] = 0.f; }
#pragma unroll
  for (int d = 0; d < 8; d++) oacc[d] = (f32x4){0.f, 0.f, 0.f, 0.f};

  const int vrow = tid >> 3;       // k-row this thread stages for V
  const int vd0 = (tid & 7) * 16;  // d start
  const float scale = 0.088388347648318447f;

  for (int kt = 0; kt < SEQ / 32; kt++) {
    __syncthreads();
    // stage K tile (swizzle via permuted global source)
#pragma unroll
    for (int t = 0; t < 2; t++) {
      int f = (w * 2 + t) * 1024 + lane * 16;
      int krow = f >> 8;
      int lslot = ((f >> 4) & 15) ^ (krow & 7);
      const u16* g = Kb + (size_t)(b * SEQ + kt * 32 + krow) * D_MODEL + h * HDIM + lslot * 8;
      gload16(g, (char*)Kt + (w * 2 + t) * 1024);
    }
    // stage V transposed into Vt[d][k] (swizzled)
    {
      const u16* g = Vb + (size_t)(b * SEQ + kt * 32 + vrow) * D_MODEL + h * HDIM + vd0;
      bf16x8 v0 = *(const bf16x8*)g;
      bf16x8 v1 = *(const bf16x8*)(g + 8);
#pragma unroll
      for (int e = 0; e < 16; e++) {
        int d = vd0 + e;
        int s = (d & 3) ^ ((d >> 4) & 3);
        u16 val = (u16)(e < 8 ? v0[e] : v1[e - 8]);
        Vt[d * 32 + (vrow ^ (s << 3))] = val;
      }
    }
    __syncthreads();

    // S = Q K^T  (two 16-key column blocks)
    f32x4 sf[2];
#pragma unroll
    for (int cb = 0; cb < 2; cb++) {
      f32x4 s = (f32x4){0.f, 0.f, 0.f, 0.f};
#pragma unroll
      for (int kb = 0; kb < 4; kb++) {
        int row = cb * 16 + lo;
        int ps = (kb * 4 + hi) ^ (row & 7);
        bf16x8 bk = *(const bf16x8*)(Kt + row * 128 + ps * 8);
        s = __builtin_amdgcn_mfma_f32_16x16x32_bf16(aQ[kb], bk, s, 0, 0, 0);
      }
      sf[cb] = s;
    }
    // online softmax (rows live on 16-lane groups)
#pragma unroll
    for (int r = 0; r < 4; r++) {
      float s0 = sf[0][r] * scale, s1 = sf[1][r] * scale;
      float tmax = fmaxf(s0, s1);
#pragma unroll
      for (int off = 1; off < 16; off <<= 1) tmax = fmaxf(tmax, __shfl_xor(tmax, off));
      float mnew = fmaxf(m_s[r], tmax);
      float alpha = __expf(m_s[r] - mnew);
      float p0 = __expf(s0 - mnew), p1 = __expf(s1 - mnew);
      float rs = p0 + p1;
#pragma unroll
      for (int off = 1; off < 16; off <<= 1) rs += __shfl_xor(rs, off);
      l_s[r] = l_s[r] * alpha + rs;
      m_s[r] = mnew;
#pragma unroll
      for (int d = 0; d < 8; d++) oacc[d][r] *= alpha;
      int prow = hi * 4 + r;
      Pl[w][prow * 40 + lo] = f2b(p0);
      Pl[w][prow * 40 + 16 + lo] = f2b(p1);
    }
    asm volatile("s_waitcnt lgkmcnt(0)" ::: "memory");
    bf16x8 aP = *(const bf16x8*)(&Pl[w][lo * 40 + hi * 8]);
#pragma unroll
    for (int db = 0; db < 8; db++) {
      int dr = db * 16 + lo;
      int s = (dr & 3) ^ (db & 3);
      bf16x8 bv = *(const bf16x8*)(Vt + dr * 32 + ((hi ^ s) * 8));
      oacc[db] = __builtin_amdgcn_mfma_f32_16x16x32_bf16(aP, bv, oacc[db], 0, 0, 0);
    }
  }
#pragma unroll
  for (int db = 0; db < 8; db++) {
#pragma unroll
    for (int r = 0; r < 4; r++) {
      size_t row = qrow0 + hi * 4 + r;
      float inv = 1.f / l_s[r];
      O[row * D_MODEL + h * HDIM + db * 16 + lo] = f2b(oacc[db][r] * inv);
    }
  }
}

extern "C" void kernel_launch(void* const* d_in, const int* in_sizes, int n_in,
                              void* d_out, int out_size, void* d_ws, size_t ws_size,
                              hipStream_t stream) {
  (void)in_sizes; (void)n_in; (void)out_size; (void)ws_size;
  const float* x  = (const float*)d_in[0];
  const float* fc = (const float*)d_in[1];
  const float* wq = (const float*)d_in[2];
  const float* wk = (const float*)d_in[3];
  const float* wv = (const float*)d_in[4];
  const float* wo = (const float*)d_in[5];
  const float* bo = (const float*)d_in[6];
  const float* w1 = (const float*)d_in[7];
  const float* w3 = (const float*)d_in[8];
  const float* w2 = (const float*)d_in[9];
  const float* ga = (const float*)d_in[10];
  const float* gf = (const float*)d_in[11];
  float* out = (float*)d_out;  // also holds hres (fp32) between the two sublayers

  // ---- workspace layout (~135 MB total) ----
  char* p = (char*)d_ws;
  auto alloc = [&](size_t bytes) { char* r = p; p += (bytes + 255) & ~(size_t)255; return r; };
  u16* xn  = (u16*)alloc((size_t)MTOK * D_MODEL * 2);  // later reused as ob
  u16* qb  = (u16*)alloc((size_t)MTOK * D_MODEL * 2);  // later reused as hn
  u16* kb  = (u16*)alloc((size_t)MTOK * D_MODEL * 2);
  u16* vb  = (u16*)alloc((size_t)MTOK * D_MODEL * 2);
  u16* x1  = (u16*)alloc((size_t)MTOK * HP * 2);
  u16* wsl = (u16*)alloc((size_t)HP * D_MODEL * 2);    // shared weight slot (max 22.5 MB)
  u16* ob = xn;
  u16* hn = qb;

  dim3 g16(D_MODEL / 128, MTOK / 128);
  dim3 gh(HP / 128, MTOK / 128);

  // ---- attention sublayer ----
  k_rmsnorm<<<MTOK, 256, 0, stream>>>(x, ga, xn);
  k_conv8<<<1024, 256, 0, stream>>>(wq, wsl, D_MODEL * D_MODEL / 8);
  k_gemm<0><<<g16, 256, 0, stream>>>(xn, wsl, qb, nullptr, nullptr, nullptr, MTOK, D_MODEL, D_MODEL);
  k_conv8<<<1024, 256, 0, stream>>>(wk, wsl, D_MODEL * D_MODEL / 8);
  k_gemm<0><<<g16, 256, 0, stream>>>(xn, wsl, kb, nullptr, nullptr, nullptr, MTOK, D_MODEL, D_MODEL);
  k_conv8<<<1024, 256, 0, stream>>>(wv, wsl, D_MODEL * D_MODEL / 8);
  k_gemm<0><<<g16, 256, 0, stream>>>(xn, wsl, vb, nullptr, nullptr, nullptr, MTOK, D_MODEL, D_MODEL);
  k_rope<<<1024, 256, 0, stream>>>(qb, kb, fc);
  dim3 gfl(SEQ / 64, BATCH * NHEADS);
  k_flash<<<gfl, 256, 0, stream>>>(qb, kb, vb, ob);  // ob overwrites xn (dead)
  k_conv8<<<1024, 256, 0, stream>>>(wo, wsl, D_MODEL * D_MODEL / 8);
  k_gemm<1><<<g16, 256, 0, stream>>>(ob, wsl, out, bo, x, nullptr, MTOK, D_MODEL, D_MODEL);

  // ---- FFN sublayer (hres lives in `out`) ----
  k_rmsnorm<<<MTOK, 256, 0, stream>>>(out, gf, hn);  // hn overwrites qb (dead)
  k_convpad<<<1024, 256, 0, stream>>>(w1, wsl, HIDDEN_, D_MODEL, HP, D_MODEL);
  k_gemm<0><<<gh, 256, 0, stream>>>(hn, wsl, x1, nullptr, nullptr, nullptr, MTOK, HP, D_MODEL);
  k_convpad<<<1024, 256, 0, stream>>>(w3, wsl, HIDDEN_, D_MODEL, HP, D_MODEL);
  k_gemm<3><<<gh, 256, 0, stream>>>(hn, wsl, x1, nullptr, nullptr, x1, MTOK, HP, D_MODEL);
  k_convpad<<<1024, 256, 0, stream>>>(w2, wsl, D_MODEL, HIDDEN_, D_MODEL, HP);
  k_gemm<2><<<g16, 256, 0, stream>>>(x1, wsl, out, nullptr, out, nullptr, MTOK, D_MODEL, HP);
}

// Round 3
// 913.258 us; speedup vs baseline: 1.1739x; 1.1739x over previous
//
#include <hip/hip_runtime.h>

#define D_MODEL 2048
#define NHEADS 16
#define HDIM 128
#define HIDDEN_ 5461
#define HP2 5632
#define BATCH 2
#define SEQ 2048
#define MTOK 4096

typedef unsigned short u16;
typedef __attribute__((ext_vector_type(8))) short bf16x8;
typedef __attribute__((ext_vector_type(4))) float f32x4;

__device__ __forceinline__ u16 f2b(float f) {
  union { float f; unsigned u; } v; v.f = f;
  return (u16)((v.u + 0x7FFFu + ((v.u >> 16) & 1u)) >> 16);
}
__device__ __forceinline__ float b2f(u16 u) {
  union { unsigned u; float f; } v; v.u = ((unsigned)u) << 16;
  return v.f;
}
__device__ __forceinline__ void gload16(const void* g, void* l) {
  __builtin_amdgcn_global_load_lds(
      (const __attribute__((address_space(1))) unsigned int*)g,
      (__attribute__((address_space(3))) unsigned int*)l, 16, 0, 0);
}

#define SB0() __builtin_amdgcn_sched_barrier(0)
#define BARRIER() do { SB0(); __builtin_amdgcn_s_barrier(); SB0(); } while (0)
#define LGKM0() do { asm volatile("s_waitcnt lgkmcnt(0)" ::: "memory"); SB0(); } while (0)

// ---------------- conversions ----------------
__global__ __launch_bounds__(256) void k_conv8(const float* __restrict__ src,
                                               u16* __restrict__ dst, int n8) {
  int stride = gridDim.x * 256;
  for (int i = blockIdx.x * 256 + threadIdx.x; i < n8; i += stride) {
    const float4* s = (const float4*)src + (size_t)i * 2;
    float4 a = s[0], b = s[1];
    bf16x8 o;
    o[0] = f2b(a.x); o[1] = f2b(a.y); o[2] = f2b(a.z); o[3] = f2b(a.w);
    o[4] = f2b(b.x); o[5] = f2b(b.y); o[6] = f2b(b.z); o[7] = f2b(b.w);
    ((bf16x8*)dst)[i] = o;
  }
}

__global__ __launch_bounds__(256) void k_convpad(const float* __restrict__ src,
                                                 u16* __restrict__ dst,
                                                 int srows, int scols, int drows, int dcols) {
  size_t n = (size_t)drows * dcols;
  size_t stride = (size_t)gridDim.x * 256;
  for (size_t i = blockIdx.x * 256 + threadIdx.x; i < n; i += stride) {
    int r = (int)(i / dcols), c = (int)(i % dcols);
    float v = (r < srows && c < scols) ? src[(size_t)r * scols + c] : 0.f;
    dst[i] = f2b(v);
  }
}

// ---------------- rmsnorm (fp32 in, bf16 out) ----------------
__global__ __launch_bounds__(256) void k_rmsnorm(const float* __restrict__ X,
                                                 const float* __restrict__ G,
                                                 u16* __restrict__ Out) {
  int row = blockIdx.x;
  int tid = threadIdx.x;
  const float4* x4 = (const float4*)(X + (size_t)row * D_MODEL);
  float4 a = x4[tid * 2], b = x4[tid * 2 + 1];
  float ss = a.x * a.x + a.y * a.y + a.z * a.z + a.w * a.w +
             b.x * b.x + b.y * b.y + b.z * b.z + b.w * b.w;
#pragma unroll
  for (int off = 1; off < 64; off <<= 1) ss += __shfl_xor(ss, off);
  __shared__ float part[4];
  if ((tid & 63) == 0) part[tid >> 6] = ss;
  __syncthreads();
  float rstd = rsqrtf((part[0] + part[1] + part[2] + part[3]) * (1.0f / D_MODEL) + 1e-6f);
  const float4* g4 = (const float4*)G;
  float4 ga = g4[tid * 2], gb = g4[tid * 2 + 1];
  bf16x8 o;
  o[0] = f2b(a.x * rstd * ga.x); o[1] = f2b(a.y * rstd * ga.y);
  o[2] = f2b(a.z * rstd * ga.z); o[3] = f2b(a.w * rstd * ga.w);
  o[4] = f2b(b.x * rstd * gb.x); o[5] = f2b(b.y * rstd * gb.y);
  o[6] = f2b(b.z * rstd * gb.z); o[7] = f2b(b.w * rstd * gb.w);
  *((bf16x8*)(Out + (size_t)row * D_MODEL) + tid) = o;
}

// ================= 256x(BN) 8-phase GEMM =================
// C[M,N] = A[M,K] * Bw[N,K]^T, bf16 in, f32 acc.
// WN = n-frags per wave (4 -> BN=256, 2 -> BN=128). 512 thr = 8 waves (2M x 4N).
// LDS: A 2buf x 2 K-planes x [256][32] bf16; B 2buf x 2 K-planes x [BN][32].
// K-planes have 64B rows -> ds_read_b128 is minimally banked, staging stays linear.
// Per K-tile: 4 phases {ds_read, stage 1 half-plane, (vmcnt ph2/ph4), barrier,
// lgkmcnt(0), setprio(1), 4*WN MFMA, setprio(0), barrier}. Counted vmcnt ledger:
// tile T stages T+1 planes (A0,B0,A1,B1) at ph1..4; vmcnt(2+WN/2) at ph2 confirms
// T's kk=1 planes, at ph4 confirms T+1's kk=0 planes. Never drains to 0.
// EPI: 0 bf16 store | 1 qkv split | 2 f32+bias+res | 3 f32+res | 4 silu(aux)*acc
template <int WN, int EPI>
__global__ __launch_bounds__(512, 2) void k_gemm2(const u16* __restrict__ A,
                                                  const u16* __restrict__ Bw,
                                                  void* __restrict__ O0,
                                                  void* __restrict__ O1,
                                                  void* __restrict__ O2,
                                                  const float* __restrict__ bias,
                                                  const float* __restrict__ res,
                                                  const u16* __restrict__ aux,
                                                  int M, int N, int K) {
  constexpr int BN = WN * 64;
  constexpr int PB = BN * 64;  // B plane bytes
  __shared__ __align__(128) char lds[65536 + 4 * PB];
  const int tid = threadIdx.x;
  const int w = tid >> 6, lane = tid & 63;
  const int lo = lane & 15, hi = lane >> 4;
  const int wr = w >> 2, wc = w & 3;

  const int ntN = N / BN;
  const int nwg = gridDim.x * gridDim.y;
  const int flat = blockIdx.y * gridDim.x + blockIdx.x;
  const int swz = (flat & 7) * (nwg >> 3) + (flat >> 3);
  const int tm = swz / ntN, tn = swz % ntN;
  const int m0 = tm * 256, n0 = tn * BN;

  auto stA = [&](int nb, int kk, int k0) {
#pragma unroll
    for (int j = 0; j < 2; ++j) {
      int row = j * 128 + (tid >> 2);
      const u16* g = A + (size_t)(m0 + row) * K + k0 + kk * 32 + (tid & 3) * 8;
      gload16(g, lds + nb * 32768 + kk * 16384 + j * 8192 + tid * 16);
    }
  };
  auto stB = [&](int nb, int kk, int k0) {
#pragma unroll
    for (int j = 0; j < WN / 2; ++j) {
      int row = j * 128 + (tid >> 2);
      const u16* g = Bw + (size_t)(n0 + row) * K + k0 + kk * 32 + (tid & 3) * 8;
      gload16(g, lds + 65536 + nb * 2 * PB + kk * PB + j * 8192 + tid * 16);
    }
  };
  auto ldA = [&](int buf, int kk, int mf) {
    return *(const bf16x8*)(lds + buf * 32768 + kk * 16384 +
                            (wr * 128 + mf * 16 + lo) * 64 + hi * 16);
  };
  auto ldB = [&](int buf, int kk, int nf) {
    return *(const bf16x8*)(lds + 65536 + buf * 2 * PB + kk * PB +
                            (wc * (WN * 16) + nf * 16 + lo) * 64 + hi * 16);
  };
#define VMCNT_CONFIRM()                                             \
  do {                                                              \
    if constexpr (WN == 4)                                          \
      asm volatile("s_waitcnt vmcnt(4)" ::: "memory");              \
    else                                                            \
      asm volatile("s_waitcnt vmcnt(3)" ::: "memory");              \
    SB0();                                                          \
  } while (0)

  f32x4 acc[8][WN];
#pragma unroll
  for (int i = 0; i < 8; i++)
#pragma unroll
    for (int j = 0; j < WN; j++) acc[i][j] = (f32x4){0.f, 0.f, 0.f, 0.f};

  // prologue: stage tile 0 (order A0,B0,A1,B1), confirm first two planes
  stA(0, 0, 0);
  stB(0, 0, 0);
  stA(0, 1, 0);
  stB(0, 1, 0);
  VMCNT_CONFIRM();
  BARRIER();

  const int KT = K / 64;
  for (int kt = 0; kt < KT; ++kt) {
    const int buf = kt & 1, nb = buf ^ 1;
    int kn = (kt + 1) * 64;
    if (kn >= K) kn = 0;  // dummy stage on last tile (never consumed)
    bf16x8 aF[4], bF[WN];

    // ---- phase 1: kk=0, m-frags 0..3 ----
#pragma unroll
    for (int i = 0; i < 4; i++) aF[i] = ldA(buf, 0, i);
#pragma unroll
    for (int j = 0; j < WN; j++) bF[j] = ldB(buf, 0, j);
    stA(nb, 0, kn);
    BARRIER();
    LGKM0();
    __builtin_amdgcn_s_setprio(1);
#pragma unroll
    for (int i = 0; i < 4; i++)
#pragma unroll
      for (int j = 0; j < WN; j++)
        acc[i][j] = __builtin_amdgcn_mfma_f32_16x16x32_bf16(aF[i], bF[j], acc[i][j], 0, 0, 0);
    __builtin_amdgcn_s_setprio(0);
    BARRIER();

    // ---- phase 2: kk=0, m-frags 4..7 (reuse bF) ----
#pragma unroll
    for (int i = 0; i < 4; i++) aF[i] = ldA(buf, 0, 4 + i);
    stB(nb, 0, kn);
    VMCNT_CONFIRM();
    BARRIER();
    LGKM0();
    __builtin_amdgcn_s_setprio(1);
#pragma unroll
    for (int i = 0; i < 4; i++)
#pragma unroll
      for (int j = 0; j < WN; j++)
        acc[4 + i][j] = __builtin_amdgcn_mfma_f32_16x16x32_bf16(aF[i], bF[j], acc[4 + i][j], 0, 0, 0);
    __builtin_amdgcn_s_setprio(0);
    BARRIER();

    // ---- phase 3: kk=1, m-frags 0..3 ----
#pragma unroll
    for (int i = 0; i < 4; i++) aF[i] = ldA(buf, 1, i);
#pragma unroll
    for (int j = 0; j < WN; j++) bF[j] = ldB(buf, 1, j);
    stA(nb, 1, kn);
    BARRIER();
    LGKM0();
    __builtin_amdgcn_s_setprio(1);
#pragma unroll
    for (int i = 0; i < 4; i++)
#pragma unroll
      for (int j = 0; j < WN; j++)
        acc[i][j] = __builtin_amdgcn_mfma_f32_16x16x32_bf16(aF[i], bF[j], acc[i][j], 0, 0, 0);
    __builtin_amdgcn_s_setprio(0);
    BARRIER();

    // ---- phase 4: kk=1, m-frags 4..7 ----
#pragma unroll
    for (int i = 0; i < 4; i++) aF[i] = ldA(buf, 1, 4 + i);
    stB(nb, 1, kn);
    VMCNT_CONFIRM();
    BARRIER();
    LGKM0();
    __builtin_amdgcn_s_setprio(1);
#pragma unroll
    for (int i = 0; i < 4; i++)
#pragma unroll
      for (int j = 0; j < WN; j++)
        acc[4 + i][j] = __builtin_amdgcn_mfma_f32_16x16x32_bf16(aF[i], bF[j], acc[4 + i][j], 0, 0, 0);
    __builtin_amdgcn_s_setprio(0);
    BARRIER();
  }

  // ---- epilogue ----
  const u16* qkvsel = nullptr;
  u16* qkvout = nullptr;
  int c0 = 0;
  if (EPI == 1) {
    int seg = n0 >> 11;
    qkvout = (u16*)(seg == 0 ? O0 : (seg == 1 ? O1 : O2));
    c0 = n0 & 2047;
  }
  (void)qkvsel;
#pragma unroll
  for (int i = 0; i < 8; i++) {
#pragma unroll
    for (int j = 0; j < WN; j++) {
      int colL = wc * (WN * 16) + j * 16 + lo;
#pragma unroll
      for (int r = 0; r < 4; r++) {
        int row = m0 + wr * 128 + i * 16 + hi * 4 + r;
        float v = acc[i][j][r];
        if (EPI == 0) {
          ((u16*)O0)[(size_t)row * N + n0 + colL] = f2b(v);
        } else if (EPI == 1) {
          qkvout[(size_t)row * 2048 + c0 + colL] = f2b(v);
        } else if (EPI == 2) {
          size_t idx = (size_t)row * N + n0 + colL;
          ((float*)O0)[idx] = v + bias[n0 + colL] + res[idx];
        } else if (EPI == 3) {
          size_t idx = (size_t)row * N + n0 + colL;
          ((float*)O0)[idx] = v + res[idx];
        } else {
          size_t idx = (size_t)row * N + n0 + colL;
          float v1 = b2f(aux[idx]);
          float sig = 1.f / (1.f + __expf(-v1));
          ((u16*)O0)[idx] = f2b(v1 * sig * v);
        }
      }
    }
  }
#undef VMCNT_CONFIRM
}

// ---------------- RoPE (in-place on bf16 q,k) ----------------
__global__ __launch_bounds__(256) void k_rope(u16* __restrict__ Qb, u16* __restrict__ Kb,
                                              const float* __restrict__ F) {
  int n = MTOK * (D_MODEL / 2);
  int stride = gridDim.x * 256;
  for (int t = blockIdx.x * 256 + threadIdx.x; t < n; t += stride) {
    int i = t & 63;
    int rest = t >> 6;
    int hh = rest & 15;
    int tok = rest >> 4;
    int s = tok & (SEQ - 1);
    float4 f = ((const float4*)F)[s * 64 + i];
    size_t off = (size_t)tok * D_MODEL + hh * HDIM + i * 2;
    float x0 = b2f(Qb[off]), x1 = b2f(Qb[off + 1]);
    Qb[off] = f2b(x0 * f.x + x1 * f.y);
    Qb[off + 1] = f2b(x0 * f.z + x1 * f.w);
    x0 = b2f(Kb[off]); x1 = b2f(Kb[off + 1]);
    Kb[off] = f2b(x0 * f.x + x1 * f.y);
    Kb[off + 1] = f2b(x0 * f.z + x1 * f.w);
  }
}

// ---------------- flash attention (non-causal), 64 q-rows/block ----------------
__global__ __launch_bounds__(256) void k_flash(const u16* __restrict__ Q,
                                               const u16* __restrict__ Kb,
                                               const u16* __restrict__ Vb,
                                               u16* __restrict__ O) {
  __shared__ u16 Kt[32 * 128];
  __shared__ u16 Vt[128 * 32];
  __shared__ u16 Pl[4][16 * 40];
  const int tid = threadIdx.x;
  const int w = tid >> 6, lane = tid & 63;
  const int lo = lane & 15, hi = lane >> 4;
  const int qt = blockIdx.x, bh = blockIdx.y;
  const int b = bh >> 4, h = bh & 15;
  const size_t qrow0 = (size_t)b * SEQ + qt * 64 + w * 16;

  bf16x8 aQ[4];
#pragma unroll
  for (int kb = 0; kb < 4; kb++)
    aQ[kb] = *(const bf16x8*)(Q + (qrow0 + lo) * D_MODEL + h * HDIM + kb * 32 + hi * 8);

  float m_s[4], l_s[4];
  f32x4 oacc[8];
#pragma unroll
  for (int r = 0; r < 4; r++) { m_s[r] = -3.0e38f; l_s[r] = 0.f; }
#pragma unroll
  for (int d = 0; d < 8; d++) oacc[d] = (f32x4){0.f, 0.f, 0.f, 0.f};

  const int vrow = tid >> 3;
  const int vd0 = (tid & 7) * 16;
  const float scale = 0.088388347648318447f;

  for (int kt = 0; kt < SEQ / 32; kt++) {
    __syncthreads();
#pragma unroll
    for (int t = 0; t < 2; t++) {
      int f = (w * 2 + t) * 1024 + lane * 16;
      int krow = f >> 8;
      int lslot = ((f >> 4) & 15) ^ (krow & 7);
      const u16* g = Kb + (size_t)(b * SEQ + kt * 32 + krow) * D_MODEL + h * HDIM + lslot * 8;
      gload16(g, (char*)Kt + (w * 2 + t) * 1024);
    }
    {
      const u16* g = Vb + (size_t)(b * SEQ + kt * 32 + vrow) * D_MODEL + h * HDIM + vd0;
      bf16x8 v0 = *(const bf16x8*)g;
      bf16x8 v1 = *(const bf16x8*)(g + 8);
#pragma unroll
      for (int e = 0; e < 16; e++) {
        int d = vd0 + e;
        int s = (d & 3) ^ ((d >> 4) & 3);
        u16 val = (u16)(e < 8 ? v0[e] : v1[e - 8]);
        Vt[d * 32 + (vrow ^ (s << 3))] = val;
      }
    }
    __syncthreads();

    f32x4 sf[2];
#pragma unroll
    for (int cb = 0; cb < 2; cb++) {
      f32x4 s = (f32x4){0.f, 0.f, 0.f, 0.f};
#pragma unroll
      for (int kb = 0; kb < 4; kb++) {
        int row = cb * 16 + lo;
        int ps = (kb * 4 + hi) ^ (row & 7);
        bf16x8 bk = *(const bf16x8*)(Kt + row * 128 + ps * 8);
        s = __builtin_amdgcn_mfma_f32_16x16x32_bf16(aQ[kb], bk, s, 0, 0, 0);
      }
      sf[cb] = s;
    }
#pragma unroll
    for (int r = 0; r < 4; r++) {
      float s0 = sf[0][r] * scale, s1 = sf[1][r] * scale;
      float tmax = fmaxf(s0, s1);
#pragma unroll
      for (int off = 1; off < 16; off <<= 1) tmax = fmaxf(tmax, __shfl_xor(tmax, off));
      float mnew = fmaxf(m_s[r], tmax);
      float alpha = __expf(m_s[r] - mnew);
      float p0 = __expf(s0 - mnew), p1 = __expf(s1 - mnew);
      float rs = p0 + p1;
#pragma unroll
      for (int off = 1; off < 16; off <<= 1) rs += __shfl_xor(rs, off);
      l_s[r] = l_s[r] * alpha + rs;
      m_s[r] = mnew;
#pragma unroll
      for (int d = 0; d < 8; d++) oacc[d][r] *= alpha;
      int prow = hi * 4 + r;
      Pl[w][prow * 40 + lo] = f2b(p0);
      Pl[w][prow * 40 + 16 + lo] = f2b(p1);
    }
    asm volatile("s_waitcnt lgkmcnt(0)" ::: "memory");
    bf16x8 aP = *(const bf16x8*)(&Pl[w][lo * 40 + hi * 8]);
#pragma unroll
    for (int db = 0; db < 8; db++) {
      int dr = db * 16 + lo;
      int s = (dr & 3) ^ (db & 3);
      bf16x8 bv = *(const bf16x8*)(Vt + dr * 32 + ((hi ^ s) * 8));
      oacc[db] = __builtin_amdgcn_mfma_f32_16x16x32_bf16(aP, bv, oacc[db], 0, 0, 0);
    }
  }
#pragma unroll
  for (int db = 0; db < 8; db++) {
#pragma unroll
    for (int r = 0; r < 4; r++) {
      size_t row = qrow0 + hi * 4 + r;
      float inv = 1.f / l_s[r];
      O[row * D_MODEL + h * HDIM + db * 16 + lo] = f2b(oacc[db][r] * inv);
    }
  }
}

extern "C" void kernel_launch(void* const* d_in, const int* in_sizes, int n_in,
                              void* d_out, int out_size, void* d_ws, size_t ws_size,
                              hipStream_t stream) {
  (void)in_sizes; (void)n_in; (void)out_size; (void)ws_size;
  const float* x  = (const float*)d_in[0];
  const float* fc = (const float*)d_in[1];
  const float* wq = (const float*)d_in[2];
  const float* wk = (const float*)d_in[3];
  const float* wv = (const float*)d_in[4];
  const float* wo = (const float*)d_in[5];
  const float* bo = (const float*)d_in[6];
  const float* w1 = (const float*)d_in[7];
  const float* w3 = (const float*)d_in[8];
  const float* w2 = (const float*)d_in[9];
  const float* ga = (const float*)d_in[10];
  const float* gf = (const float*)d_in[11];
  float* out = (float*)d_out;  // also holds hres (fp32) between sublayers

  // ---- workspace (~135 MB) ----
  char* p = (char*)d_ws;
  auto alloc = [&](size_t bytes) { char* r = p; p += (bytes + 255) & ~(size_t)255; return r; };
  u16* xn  = (u16*)alloc((size_t)MTOK * D_MODEL * 2);  // reused as ob
  u16* qb  = (u16*)alloc((size_t)MTOK * D_MODEL * 2);  // reused as hn
  u16* kb  = (u16*)alloc((size_t)MTOK * D_MODEL * 2);
  u16* vb  = (u16*)alloc((size_t)MTOK * D_MODEL * 2);
  u16* x1  = (u16*)alloc((size_t)MTOK * HP2 * 2);
  u16* wsl = (u16*)alloc((size_t)3 * D_MODEL * D_MODEL * 2);  // 25.2 MB shared weight slot
  u16* ob = xn;
  u16* hn = qb;

  // ---- attention sublayer ----
  k_rmsnorm<<<MTOK, 256, 0, stream>>>(x, ga, xn);
  // QKV fused: wsl = [wq; wk; wv]  (6144 x 2048)
  k_conv8<<<1024, 256, 0, stream>>>(wq, wsl, D_MODEL * D_MODEL / 8);
  k_conv8<<<1024, 256, 0, stream>>>(wk, wsl + (size_t)D_MODEL * D_MODEL, D_MODEL * D_MODEL / 8);
  k_conv8<<<1024, 256, 0, stream>>>(wv, wsl + (size_t)2 * D_MODEL * D_MODEL, D_MODEL * D_MODEL / 8);
  k_gemm2<4, 1><<<dim3(6144 / 256, MTOK / 256), 512, 0, stream>>>(
      xn, wsl, qb, kb, vb, nullptr, nullptr, nullptr, MTOK, 6144, D_MODEL);
  k_rope<<<1024, 256, 0, stream>>>(qb, kb, fc);
  dim3 gfl(SEQ / 64, BATCH * NHEADS);
  k_flash<<<gfl, 256, 0, stream>>>(qb, kb, vb, ob);  // ob overwrites xn (dead)
  k_conv8<<<1024, 256, 0, stream>>>(wo, wsl, D_MODEL * D_MODEL / 8);
  k_gemm2<2, 2><<<dim3(2048 / 128, MTOK / 256), 512, 0, stream>>>(
      ob, wsl, out, nullptr, nullptr, bo, x, nullptr, MTOK, D_MODEL, D_MODEL);

  // ---- FFN sublayer (hres lives in `out`) ----
  k_rmsnorm<<<MTOK, 256, 0, stream>>>(out, gf, hn);  // hn overwrites qb (dead)
  k_convpad<<<1024, 256, 0, stream>>>(w1, wsl, HIDDEN_, D_MODEL, HP2, D_MODEL);
  k_gemm2<4, 0><<<dim3(HP2 / 256, MTOK / 256), 512, 0, stream>>>(
      hn, wsl, x1, nullptr, nullptr, nullptr, nullptr, nullptr, MTOK, HP2, D_MODEL);
  k_convpad<<<1024, 256, 0, stream>>>(w3, wsl, HIDDEN_, D_MODEL, HP2, D_MODEL);
  k_gemm2<4, 4><<<dim3(HP2 / 256, MTOK / 256), 512, 0, stream>>>(
      hn, wsl, x1, nullptr, nullptr, nullptr, nullptr, x1, MTOK, HP2, D_MODEL);
  k_convpad<<<1024, 256, 0, stream>>>(w2, wsl, D_MODEL, HIDDEN_, D_MODEL, HP2);
  k_gemm2<2, 3><<<dim3(2048 / 128, MTOK / 256), 512, 0, stream>>>(
      x1, wsl, out, nullptr, nullptr, nullptr, out, nullptr, MTOK, D_MODEL, HP2);
}

// Round 4
// 852.793 us; speedup vs baseline: 1.2571x; 1.0709x over previous
//
#include <hip/hip_runtime.h>

#define D_MODEL 2048
#define NHEADS 16
#define HDIM 128
#define HIDDEN_ 5461
#define HP2 5632
#define BATCH 2
#define SEQ 2048
#define MTOK 4096

typedef unsigned short u16;
typedef __attribute__((ext_vector_type(8))) short bf16x8;
typedef __attribute__((ext_vector_type(4))) float f32x4;

__device__ __forceinline__ u16 f2b(float f) {
  union { float f; unsigned u; } v; v.f = f;
  return (u16)((v.u + 0x7FFFu + ((v.u >> 16) & 1u)) >> 16);
}
__device__ __forceinline__ float b2f(u16 u) {
  union { unsigned u; float f; } v; v.u = ((unsigned)u) << 16;
  return v.f;
}
__device__ __forceinline__ void gload16(const void* g, void* l) {
  __builtin_amdgcn_global_load_lds(
      (const __attribute__((address_space(1))) unsigned int*)g,
      (__attribute__((address_space(3))) unsigned int*)l, 16, 0, 0);
}

#define SB0() __builtin_amdgcn_sched_barrier(0)
#define BARRIER() do { SB0(); __builtin_amdgcn_s_barrier(); SB0(); } while (0)
#define LGKM0() do { asm volatile("s_waitcnt lgkmcnt(0)" ::: "memory"); SB0(); } while (0)

// ---------------- conversions ----------------
__global__ __launch_bounds__(256) void k_conv8(const float* __restrict__ src,
                                               u16* __restrict__ dst, int n8) {
  int stride = gridDim.x * 256;
  for (int i = blockIdx.x * 256 + threadIdx.x; i < n8; i += stride) {
    const float4* s = (const float4*)src + (size_t)i * 2;
    float4 a = s[0], b = s[1];
    bf16x8 o;
    o[0] = f2b(a.x); o[1] = f2b(a.y); o[2] = f2b(a.z); o[3] = f2b(a.w);
    o[4] = f2b(b.x); o[5] = f2b(b.y); o[6] = f2b(b.z); o[7] = f2b(b.w);
    ((bf16x8*)dst)[i] = o;
  }
}

__global__ __launch_bounds__(256) void k_convpad(const float* __restrict__ src,
                                                 u16* __restrict__ dst,
                                                 int srows, int scols, int drows, int dcols) {
  size_t n = (size_t)drows * dcols;
  size_t stride = (size_t)gridDim.x * 256;
  for (size_t i = blockIdx.x * 256 + threadIdx.x; i < n; i += stride) {
    int r = (int)(i / dcols), c = (int)(i % dcols);
    float v = (r < srows && c < scols) ? src[(size_t)r * scols + c] : 0.f;
    dst[i] = f2b(v);
  }
}

// ---------------- rmsnorm (fp32 in, bf16 out) ----------------
__global__ __launch_bounds__(256) void k_rmsnorm(const float* __restrict__ X,
                                                 const float* __restrict__ G,
                                                 u16* __restrict__ Out) {
  int row = blockIdx.x;
  int tid = threadIdx.x;
  const float4* x4 = (const float4*)(X + (size_t)row * D_MODEL);
  float4 a = x4[tid * 2], b = x4[tid * 2 + 1];
  float ss = a.x * a.x + a.y * a.y + a.z * a.z + a.w * a.w +
             b.x * b.x + b.y * b.y + b.z * b.z + b.w * b.w;
#pragma unroll
  for (int off = 1; off < 64; off <<= 1) ss += __shfl_xor(ss, off);
  __shared__ float part[4];
  if ((tid & 63) == 0) part[tid >> 6] = ss;
  __syncthreads();
  float rstd = rsqrtf((part[0] + part[1] + part[2] + part[3]) * (1.0f / D_MODEL) + 1e-6f);
  const float4* g4 = (const float4*)G;
  float4 ga = g4[tid * 2], gb = g4[tid * 2 + 1];
  bf16x8 o;
  o[0] = f2b(a.x * rstd * ga.x); o[1] = f2b(a.y * rstd * ga.y);
  o[2] = f2b(a.z * rstd * ga.z); o[3] = f2b(a.w * rstd * ga.w);
  o[4] = f2b(b.x * rstd * gb.x); o[5] = f2b(b.y * rstd * gb.y);
  o[6] = f2b(b.z * rstd * gb.z); o[7] = f2b(b.w * rstd * gb.w);
  *((bf16x8*)(Out + (size_t)row * D_MODEL) + tid) = o;
}

// ================= 256x(BN) 8-phase GEMM (unchanged from R3) =================
template <int WN, int EPI>
__global__ __launch_bounds__(512, 2) void k_gemm2(const u16* __restrict__ A,
                                                  const u16* __restrict__ Bw,
                                                  void* __restrict__ O0,
                                                  void* __restrict__ O1,
                                                  void* __restrict__ O2,
                                                  const float* __restrict__ bias,
                                                  const float* __restrict__ res,
                                                  const u16* __restrict__ aux,
                                                  int M, int N, int K) {
  constexpr int BN = WN * 64;
  constexpr int PB = BN * 64;  // B plane bytes
  __shared__ __align__(128) char lds[65536 + 4 * PB];
  const int tid = threadIdx.x;
  const int w = tid >> 6, lane = tid & 63;
  const int lo = lane & 15, hi = lane >> 4;
  const int wr = w >> 2, wc = w & 3;

  const int ntN = N / BN;
  const int nwg = gridDim.x * gridDim.y;
  const int flat = blockIdx.y * gridDim.x + blockIdx.x;
  const int swz = (flat & 7) * (nwg >> 3) + (flat >> 3);
  const int tm = swz / ntN, tn = swz % ntN;
  const int m0 = tm * 256, n0 = tn * BN;

  auto stA = [&](int nb, int kk, int k0) {
#pragma unroll
    for (int j = 0; j < 2; ++j) {
      int row = j * 128 + (tid >> 2);
      const u16* g = A + (size_t)(m0 + row) * K + k0 + kk * 32 + (tid & 3) * 8;
      gload16(g, lds + nb * 32768 + kk * 16384 + j * 8192 + tid * 16);
    }
  };
  auto stB = [&](int nb, int kk, int k0) {
#pragma unroll
    for (int j = 0; j < WN / 2; ++j) {
      int row = j * 128 + (tid >> 2);
      const u16* g = Bw + (size_t)(n0 + row) * K + k0 + kk * 32 + (tid & 3) * 8;
      gload16(g, lds + 65536 + nb * 2 * PB + kk * PB + j * 8192 + tid * 16);
    }
  };
  auto ldA = [&](int buf, int kk, int mf) {
    return *(const bf16x8*)(lds + buf * 32768 + kk * 16384 +
                            (wr * 128 + mf * 16 + lo) * 64 + hi * 16);
  };
  auto ldB = [&](int buf, int kk, int nf) {
    return *(const bf16x8*)(lds + 65536 + buf * 2 * PB + kk * PB +
                            (wc * (WN * 16) + nf * 16 + lo) * 64 + hi * 16);
  };
#define VMCNT_CONFIRM()                                             \
  do {                                                              \
    if constexpr (WN == 4)                                          \
      asm volatile("s_waitcnt vmcnt(4)" ::: "memory");              \
    else                                                            \
      asm volatile("s_waitcnt vmcnt(3)" ::: "memory");              \
    SB0();                                                          \
  } while (0)

  f32x4 acc[8][WN];
#pragma unroll
  for (int i = 0; i < 8; i++)
#pragma unroll
    for (int j = 0; j < WN; j++) acc[i][j] = (f32x4){0.f, 0.f, 0.f, 0.f};

  stA(0, 0, 0);
  stB(0, 0, 0);
  stA(0, 1, 0);
  stB(0, 1, 0);
  VMCNT_CONFIRM();
  BARRIER();

  const int KT = K / 64;
  for (int kt = 0; kt < KT; ++kt) {
    const int buf = kt & 1, nb = buf ^ 1;
    int kn = (kt + 1) * 64;
    if (kn >= K) kn = 0;  // dummy stage on last tile (never consumed)
    bf16x8 aF[4], bF[WN];

    // ---- phase 1: kk=0, m-frags 0..3 ----
#pragma unroll
    for (int i = 0; i < 4; i++) aF[i] = ldA(buf, 0, i);
#pragma unroll
    for (int j = 0; j < WN; j++) bF[j] = ldB(buf, 0, j);
    stA(nb, 0, kn);
    BARRIER();
    LGKM0();
    __builtin_amdgcn_s_setprio(1);
#pragma unroll
    for (int i = 0; i < 4; i++)
#pragma unroll
      for (int j = 0; j < WN; j++)
        acc[i][j] = __builtin_amdgcn_mfma_f32_16x16x32_bf16(aF[i], bF[j], acc[i][j], 0, 0, 0);
    __builtin_amdgcn_s_setprio(0);
    BARRIER();

    // ---- phase 2: kk=0, m-frags 4..7 ----
#pragma unroll
    for (int i = 0; i < 4; i++) aF[i] = ldA(buf, 0, 4 + i);
    stB(nb, 0, kn);
    VMCNT_CONFIRM();
    BARRIER();
    LGKM0();
    __builtin_amdgcn_s_setprio(1);
#pragma unroll
    for (int i = 0; i < 4; i++)
#pragma unroll
      for (int j = 0; j < WN; j++)
        acc[4 + i][j] = __builtin_amdgcn_mfma_f32_16x16x32_bf16(aF[i], bF[j], acc[4 + i][j], 0, 0, 0);
    __builtin_amdgcn_s_setprio(0);
    BARRIER();

    // ---- phase 3: kk=1, m-frags 0..3 ----
#pragma unroll
    for (int i = 0; i < 4; i++) aF[i] = ldA(buf, 1, i);
#pragma unroll
    for (int j = 0; j < WN; j++) bF[j] = ldB(buf, 1, j);
    stA(nb, 1, kn);
    BARRIER();
    LGKM0();
    __builtin_amdgcn_s_setprio(1);
#pragma unroll
    for (int i = 0; i < 4; i++)
#pragma unroll
      for (int j = 0; j < WN; j++)
        acc[i][j] = __builtin_amdgcn_mfma_f32_16x16x32_bf16(aF[i], bF[j], acc[i][j], 0, 0, 0);
    __builtin_amdgcn_s_setprio(0);
    BARRIER();

    // ---- phase 4: kk=1, m-frags 4..7 ----
#pragma unroll
    for (int i = 0; i < 4; i++) aF[i] = ldA(buf, 1, 4 + i);
    stB(nb, 1, kn);
    VMCNT_CONFIRM();
    BARRIER();
    LGKM0();
    __builtin_amdgcn_s_setprio(1);
#pragma unroll
    for (int i = 0; i < 4; i++)
#pragma unroll
      for (int j = 0; j < WN; j++)
        acc[4 + i][j] = __builtin_amdgcn_mfma_f32_16x16x32_bf16(aF[i], bF[j], acc[4 + i][j], 0, 0, 0);
    __builtin_amdgcn_s_setprio(0);
    BARRIER();
  }

  // ---- epilogue ----
  u16* qkvout = nullptr;
  int c0 = 0;
  if (EPI == 1) {
    int seg = n0 >> 11;
    qkvout = (u16*)(seg == 0 ? O0 : (seg == 1 ? O1 : O2));
    c0 = n0 & 2047;
  }
#pragma unroll
  for (int i = 0; i < 8; i++) {
#pragma unroll
    for (int j = 0; j < WN; j++) {
      int colL = wc * (WN * 16) + j * 16 + lo;
#pragma unroll
      for (int r = 0; r < 4; r++) {
        int row = m0 + wr * 128 + i * 16 + hi * 4 + r;
        float v = acc[i][j][r];
        if (EPI == 0) {
          ((u16*)O0)[(size_t)row * N + n0 + colL] = f2b(v);
        } else if (EPI == 1) {
          qkvout[(size_t)row * 2048 + c0 + colL] = f2b(v);
        } else if (EPI == 2) {
          size_t idx = (size_t)row * N + n0 + colL;
          ((float*)O0)[idx] = v + bias[n0 + colL] + res[idx];
        } else if (EPI == 3) {
          size_t idx = (size_t)row * N + n0 + colL;
          ((float*)O0)[idx] = v + res[idx];
        } else {
          size_t idx = (size_t)row * N + n0 + colL;
          float v1 = b2f(aux[idx]);
          float sig = 1.f / (1.f + __expf(-v1));
          ((u16*)O0)[idx] = f2b(v1 * sig * v);
        }
      }
    }
  }
#undef VMCNT_CONFIRM
}

// ---------------- RoPE (in-place on bf16 q,k) ----------------
__global__ __launch_bounds__(256) void k_rope(u16* __restrict__ Qb, u16* __restrict__ Kb,
                                              const float* __restrict__ F) {
  int n = MTOK * (D_MODEL / 2);
  int stride = gridDim.x * 256;
  for (int t = blockIdx.x * 256 + threadIdx.x; t < n; t += stride) {
    int i = t & 63;
    int rest = t >> 6;
    int hh = rest & 15;
    int tok = rest >> 4;
    int s = tok & (SEQ - 1);
    float4 f = ((const float4*)F)[s * 64 + i];
    size_t off = (size_t)tok * D_MODEL + hh * HDIM + i * 2;
    float x0 = b2f(Qb[off]), x1 = b2f(Qb[off + 1]);
    Qb[off] = f2b(x0 * f.x + x1 * f.y);
    Qb[off + 1] = f2b(x0 * f.z + x1 * f.w);
    x0 = b2f(Kb[off]); x1 = b2f(Kb[off + 1]);
    Kb[off] = f2b(x0 * f.x + x1 * f.y);
    Kb[off + 1] = f2b(x0 * f.z + x1 * f.w);
  }
}

// ---------------- V transpose: V[4096tok][2048] -> VT[32bh][128d][2048s] ----------------
__global__ __launch_bounds__(256) void k_vt(const u16* __restrict__ V, u16* __restrict__ VT) {
  __shared__ u16 t[64][72];
  const int stile = blockIdx.x;  // 32 s-tiles
  const int bh = blockIdx.y;     // 32
  const int dz = blockIdx.z;     // 2 d-halves
  const int b = bh >> 4, h = bh & 15;
  const int tok0 = b * SEQ + stile * 64;
  const int d0 = dz * 64;
  const int tid = threadIdx.x;
#pragma unroll
  for (int p = 0; p < 2; p++) {
    int idx = p * 256 + tid;
    int row = idx >> 3, seg = idx & 7;
    bf16x8 v = *(const bf16x8*)(V + (size_t)(tok0 + row) * D_MODEL + h * HDIM + d0 + seg * 8);
    *(bf16x8*)(&t[row][seg * 8]) = v;
  }
  __syncthreads();
#pragma unroll
  for (int p = 0; p < 2; p++) {
    int idx = p * 256 + tid;
    int dr = idx >> 3, seg = idx & 7;
    bf16x8 o;
#pragma unroll
    for (int e = 0; e < 8; e++) o[e] = t[seg * 8 + e][dr];
    *(bf16x8*)(VT + ((size_t)bh * HDIM + d0 + dr) * SEQ + stile * 64 + seg * 8) = o;
  }
}

// ---------------- flash attention v2: 64 q-rows/block, KVBLK=64 ----------------
// Kt [64 key][128 d] 256B rows, 16B-slot swizzle ps = s ^ (row&7)
// Vt [128 d][64 k]  128B rows,  16B-slot swizzle ps = s ^ (row&7)
// staged via global_load_lds with pre-swizzled global source (linear LDS dest).
__global__ __launch_bounds__(256) void k_flash2(const u16* __restrict__ Q,
                                                const u16* __restrict__ Kb,
                                                const u16* __restrict__ VT,
                                                u16* __restrict__ O) {
  __shared__ u16 Kt[64 * 128];
  __shared__ u16 Vt[128 * 64];
  __shared__ u16 Pl[4][16 * 72];
  const int tid = threadIdx.x;
  const int w = tid >> 6, lane = tid & 63;
  const int lo = lane & 15, hi = lane >> 4;
  const int qt = blockIdx.x, bh = blockIdx.y;
  const int b = bh >> 4, h = bh & 15;
  const size_t qrow0 = (size_t)b * SEQ + qt * 64 + w * 16;
  const float SC = 0.08838834764831845f * 1.4426950408889634f;  // scale * log2(e)

  bf16x8 aQ[4];
#pragma unroll
  for (int kb = 0; kb < 4; kb++)
    aQ[kb] = *(const bf16x8*)(Q + (qrow0 + lo) * D_MODEL + h * HDIM + kb * 32 + hi * 8);

  float m_s[4], l_s[4];
  f32x4 oacc[8];
#pragma unroll
  for (int r = 0; r < 4; r++) { m_s[r] = -3.0e38f; l_s[r] = 0.f; }
#pragma unroll
  for (int d = 0; d < 8; d++) oacc[d] = (f32x4){0.f, 0.f, 0.f, 0.f};

  // staging source offsets (swizzle-inverted), constant across kt
  const int krowL = tid >> 4;                               // K: local row per pass (16/pass)
  const int kslot = (tid & 15) ^ (krowL & 7);               // logical 16B slot
  const int vrowL = tid >> 3;                               // V: local row per pass (32/pass)
  const int vslot = (tid & 7) ^ (vrowL & 7);
  const u16* Kbase = Kb + (size_t)b * SEQ * D_MODEL + h * HDIM;
  const u16* Vbase = VT + (size_t)bh * HDIM * SEQ;

  for (int kt = 0; kt < SEQ / 64; kt++) {
    __syncthreads();
    // stage K tile: 4 passes x 256thr x 16B
#pragma unroll
    for (int t = 0; t < 4; t++) {
      int row = t * 16 + krowL;
      const u16* g = Kbase + (size_t)(kt * 64 + row) * D_MODEL + kslot * 8;
      gload16(g, (char*)Kt + t * 4096 + tid * 16);
    }
    // stage V^T tile
#pragma unroll
    for (int t = 0; t < 4; t++) {
      int row = t * 32 + vrowL;
      const u16* g = Vbase + (size_t)row * SEQ + kt * 64 + vslot * 8;
      gload16(g, (char*)Vt + t * 4096 + tid * 16);
    }
    __syncthreads();

    // ---- QK^T: 4 key-column blocks ----
    f32x4 sf[4];
#pragma unroll
    for (int cb = 0; cb < 4; cb++) {
      f32x4 s = (f32x4){0.f, 0.f, 0.f, 0.f};
#pragma unroll
      for (int kb = 0; kb < 4; kb++) {
        int row = cb * 16 + lo;
        int ps = (kb * 4 + hi) ^ (lo & 7);
        bf16x8 bk = *(const bf16x8*)(Kt + row * 128 + ps * 8);
        s = __builtin_amdgcn_mfma_f32_16x16x32_bf16(aQ[kb], bk, s, 0, 0, 0);
      }
      sf[cb] = s;
    }

    // ---- online softmax (exp2 domain), defer-max ----
    float tm[4];
    bool okl = true;
#pragma unroll
    for (int r = 0; r < 4; r++) {
      float s0 = sf[0][r] * SC, s1 = sf[1][r] * SC;
      float s2 = sf[2][r] * SC, s3 = sf[3][r] * SC;
      sf[0][r] = s0; sf[1][r] = s1; sf[2][r] = s2; sf[3][r] = s3;
      float t = fmaxf(fmaxf(s0, s1), fmaxf(s2, s3));
#pragma unroll
      for (int off = 1; off < 16; off <<= 1) t = fmaxf(t, __shfl_xor(t, off));
      tm[r] = t;
      okl = okl && (t - m_s[r] <= 11.5f);
    }
    if (__all(okl)) {
#pragma unroll
      for (int r = 0; r < 4; r++) {
        float p0 = exp2f(sf[0][r] - m_s[r]), p1 = exp2f(sf[1][r] - m_s[r]);
        float p2 = exp2f(sf[2][r] - m_s[r]), p3 = exp2f(sf[3][r] - m_s[r]);
        float rs = (p0 + p1) + (p2 + p3);
#pragma unroll
        for (int off = 1; off < 16; off <<= 1) rs += __shfl_xor(rs, off);
        l_s[r] += rs;
        int prow = hi * 4 + r;
        Pl[w][prow * 72 + lo] = f2b(p0);
        Pl[w][prow * 72 + 16 + lo] = f2b(p1);
        Pl[w][prow * 72 + 32 + lo] = f2b(p2);
        Pl[w][prow * 72 + 48 + lo] = f2b(p3);
      }
    } else {
#pragma unroll
      for (int r = 0; r < 4; r++) {
        float mnew = fmaxf(m_s[r], tm[r]);
        float alpha = exp2f(m_s[r] - mnew);
        float p0 = exp2f(sf[0][r] - mnew), p1 = exp2f(sf[1][r] - mnew);
        float p2 = exp2f(sf[2][r] - mnew), p3 = exp2f(sf[3][r] - mnew);
        float rs = (p0 + p1) + (p2 + p3);
#pragma unroll
        for (int off = 1; off < 16; off <<= 1) rs += __shfl_xor(rs, off);
        l_s[r] = l_s[r] * alpha + rs;
        m_s[r] = mnew;
#pragma unroll
        for (int d = 0; d < 8; d++) oacc[d][r] *= alpha;
        int prow = hi * 4 + r;
        Pl[w][prow * 72 + lo] = f2b(p0);
        Pl[w][prow * 72 + 16 + lo] = f2b(p1);
        Pl[w][prow * 72 + 32 + lo] = f2b(p2);
        Pl[w][prow * 72 + 48 + lo] = f2b(p3);
      }
    }
    asm volatile("s_waitcnt lgkmcnt(0)" ::: "memory");
    bf16x8 aP[2];
#pragma unroll
    for (int ks = 0; ks < 2; ks++)
      aP[ks] = *(const bf16x8*)(&Pl[w][lo * 72 + ks * 32 + hi * 8]);
    // ---- PV: 8 d-blocks x 2 k-frags ----
#pragma unroll
    for (int db = 0; db < 8; db++) {
#pragma unroll
      for (int ks = 0; ks < 2; ks++) {
        int row = db * 16 + lo;
        int ps = (ks * 4 + hi) ^ (lo & 7);
        bf16x8 bv = *(const bf16x8*)(Vt + row * 64 + ps * 8);
        oacc[db] = __builtin_amdgcn_mfma_f32_16x16x32_bf16(aP[ks], bv, oacc[db], 0, 0, 0);
      }
    }
  }
#pragma unroll
  for (int db = 0; db < 8; db++) {
#pragma unroll
    for (int r = 0; r < 4; r++) {
      size_t row = qrow0 + hi * 4 + r;
      float inv = 1.f / l_s[r];
      O[row * D_MODEL + h * HDIM + db * 16 + lo] = f2b(oacc[db][r] * inv);
    }
  }
}

extern "C" void kernel_launch(void* const* d_in, const int* in_sizes, int n_in,
                              void* d_out, int out_size, void* d_ws, size_t ws_size,
                              hipStream_t stream) {
  (void)in_sizes; (void)n_in; (void)out_size; (void)ws_size;
  const float* x  = (const float*)d_in[0];
  const float* fc = (const float*)d_in[1];
  const float* wq = (const float*)d_in[2];
  const float* wk = (const float*)d_in[3];
  const float* wv = (const float*)d_in[4];
  const float* wo = (const float*)d_in[5];
  const float* bo = (const float*)d_in[6];
  const float* w1 = (const float*)d_in[7];
  const float* w3 = (const float*)d_in[8];
  const float* w2 = (const float*)d_in[9];
  const float* ga = (const float*)d_in[10];
  const float* gf = (const float*)d_in[11];
  float* out = (float*)d_out;  // also holds hres (fp32) between sublayers

  // ---- workspace (~139 MB) ----
  char* p = (char*)d_ws;
  auto alloc = [&](size_t bytes) { char* r = p; p += (bytes + 255) & ~(size_t)255; return r; };
  u16* xn  = (u16*)alloc((size_t)MTOK * D_MODEL * 2);  // reused as vbt after QKV GEMM
  u16* qb  = (u16*)alloc((size_t)MTOK * D_MODEL * 2);  // reused as hn after flash
  u16* kb  = (u16*)alloc((size_t)MTOK * D_MODEL * 2);
  u16* vb  = (u16*)alloc((size_t)MTOK * D_MODEL * 2);  // reused as ob after k_vt
  u16* x1  = (u16*)alloc((size_t)MTOK * HP2 * 2);
  u16* wsl = (u16*)alloc((size_t)3 * D_MODEL * D_MODEL * 2);  // 25.2 MB shared weight slot
  u16* vbt = xn;  // [32 bh][128 d][2048 s]
  u16* ob  = vb;
  u16* hn  = qb;

  // ---- attention sublayer ----
  k_rmsnorm<<<MTOK, 256, 0, stream>>>(x, ga, xn);
  k_conv8<<<1024, 256, 0, stream>>>(wq, wsl, D_MODEL * D_MODEL / 8);
  k_conv8<<<1024, 256, 0, stream>>>(wk, wsl + (size_t)D_MODEL * D_MODEL, D_MODEL * D_MODEL / 8);
  k_conv8<<<1024, 256, 0, stream>>>(wv, wsl + (size_t)2 * D_MODEL * D_MODEL, D_MODEL * D_MODEL / 8);
  k_gemm2<4, 1><<<dim3(6144 / 256, MTOK / 256), 512, 0, stream>>>(
      xn, wsl, qb, kb, vb, nullptr, nullptr, nullptr, MTOK, 6144, D_MODEL);
  k_rope<<<1024, 256, 0, stream>>>(qb, kb, fc);
  k_vt<<<dim3(SEQ / 64, BATCH * NHEADS, 2), 256, 0, stream>>>(vb, vbt);  // vbt overwrites xn (dead)
  dim3 gfl(SEQ / 64, BATCH * NHEADS);
  k_flash2<<<gfl, 256, 0, stream>>>(qb, kb, vbt, ob);  // ob overwrites vb (dead after k_vt)
  k_conv8<<<1024, 256, 0, stream>>>(wo, wsl, D_MODEL * D_MODEL / 8);
  k_gemm2<2, 2><<<dim3(2048 / 128, MTOK / 256), 512, 0, stream>>>(
      ob, wsl, out, nullptr, nullptr, bo, x, nullptr, MTOK, D_MODEL, D_MODEL);

  // ---- FFN sublayer (hres lives in `out`) ----
  k_rmsnorm<<<MTOK, 256, 0, stream>>>(out, gf, hn);  // hn overwrites qb (dead)
  k_convpad<<<1024, 256, 0, stream>>>(w1, wsl, HIDDEN_, D_MODEL, HP2, D_MODEL);
  k_gemm2<4, 0><<<dim3(HP2 / 256, MTOK / 256), 512, 0, stream>>>(
      hn, wsl, x1, nullptr, nullptr, nullptr, nullptr, nullptr, MTOK, HP2, D_MODEL);
  k_convpad<<<1024, 256, 0, stream>>>(w3, wsl, HIDDEN_, D_MODEL, HP2, D_MODEL);
  k_gemm2<4, 4><<<dim3(HP2 / 256, MTOK / 256), 512, 0, stream>>>(
      hn, wsl, x1, nullptr, nullptr, nullptr, nullptr, x1, MTOK, HP2, D_MODEL);
  k_convpad<<<1024, 256, 0, stream>>>(w2, wsl, D_MODEL, HIDDEN_, D_MODEL, HP2);
  k_gemm2<2, 3><<<dim3(2048 / 128, MTOK / 256), 512, 0, stream>>>(
      x1, wsl, out, nullptr, nullptr, nullptr, out, nullptr, MTOK, D_MODEL, HP2);
}

// Round 5
// 819.342 us; speedup vs baseline: 1.3084x; 1.0408x over previous
//
#include <hip/hip_runtime.h>

#define D_MODEL 2048
#define NHEADS 16
#define HDIM 128
#define HIDDEN_ 5461
#define HP2 5632
#define BATCH 2
#define SEQ 2048
#define MTOK 4096

typedef unsigned short u16;
typedef __attribute__((ext_vector_type(8))) short bf16x8;
typedef __attribute__((ext_vector_type(4))) float f32x4;
typedef __attribute__((ext_vector_type(4))) short s16x4;

__device__ __forceinline__ u16 f2b(float f) {
  union { float f; unsigned u; } v; v.f = f;
  return (u16)((v.u + 0x7FFFu + ((v.u >> 16) & 1u)) >> 16);
}
__device__ __forceinline__ float b2f(u16 u) {
  union { unsigned u; float f; } v; v.u = ((unsigned)u) << 16;
  return v.f;
}
__device__ __forceinline__ void gload16(const void* g, void* l) {
  __builtin_amdgcn_global_load_lds(
      (const __attribute__((address_space(1))) unsigned int*)g,
      (__attribute__((address_space(3))) unsigned int*)l, 16, 0, 0);
}

#define SB0() __builtin_amdgcn_sched_barrier(0)
#define BARRIER() do { SB0(); __builtin_amdgcn_s_barrier(); SB0(); } while (0)
#define LGKM0() do { asm volatile("s_waitcnt lgkmcnt(0)" ::: "memory"); SB0(); } while (0)

// ---------------- conversions ----------------
__global__ __launch_bounds__(256) void k_conv8(const float* __restrict__ src,
                                               u16* __restrict__ dst, int n8) {
  int stride = gridDim.x * 256;
  for (int i = blockIdx.x * 256 + threadIdx.x; i < n8; i += stride) {
    const float4* s = (const float4*)src + (size_t)i * 2;
    float4 a = s[0], b = s[1];
    bf16x8 o;
    o[0] = f2b(a.x); o[1] = f2b(a.y); o[2] = f2b(a.z); o[3] = f2b(a.w);
    o[4] = f2b(b.x); o[5] = f2b(b.y); o[6] = f2b(b.z); o[7] = f2b(b.w);
    ((bf16x8*)dst)[i] = o;
  }
}

// three same-size fp32->bf16 conversions in one launch (seg = i>>19 since n8=2^19)
__global__ __launch_bounds__(256) void k_conv3(const float* __restrict__ s0,
                                               const float* __restrict__ s1,
                                               const float* __restrict__ s2,
                                               u16* __restrict__ dst) {
  const int n8 = D_MODEL * D_MODEL / 8;  // 524288 = 2^19
  int total = 3 * n8;
  int stride = gridDim.x * 256;
  for (int i = blockIdx.x * 256 + threadIdx.x; i < total; i += stride) {
    int seg = i >> 19, j = i & (n8 - 1);
    const float* s = (seg == 0) ? s0 : (seg == 1 ? s1 : s2);
    const float4* sp = (const float4*)s + (size_t)j * 2;
    float4 a = sp[0], b = sp[1];
    bf16x8 o;
    o[0] = f2b(a.x); o[1] = f2b(a.y); o[2] = f2b(a.z); o[3] = f2b(a.w);
    o[4] = f2b(b.x); o[5] = f2b(b.y); o[6] = f2b(b.z); o[7] = f2b(b.w);
    ((bf16x8*)dst)[i] = o;
  }
}

__global__ __launch_bounds__(256) void k_convpad(const float* __restrict__ src,
                                                 u16* __restrict__ dst,
                                                 int srows, int scols, int drows, int dcols) {
  size_t n = (size_t)drows * dcols;
  size_t stride = (size_t)gridDim.x * 256;
  for (size_t i = blockIdx.x * 256 + threadIdx.x; i < n; i += stride) {
    int r = (int)(i / dcols), c = (int)(i % dcols);
    float v = (r < srows && c < scols) ? src[(size_t)r * scols + c] : 0.f;
    dst[i] = f2b(v);
  }
}

// ---------------- rmsnorm (fp32 in, bf16 out) ----------------
__global__ __launch_bounds__(256) void k_rmsnorm(const float* __restrict__ X,
                                                 const float* __restrict__ G,
                                                 u16* __restrict__ Out) {
  int row = blockIdx.x;
  int tid = threadIdx.x;
  const float4* x4 = (const float4*)(X + (size_t)row * D_MODEL);
  float4 a = x4[tid * 2], b = x4[tid * 2 + 1];
  float ss = a.x * a.x + a.y * a.y + a.z * a.z + a.w * a.w +
             b.x * b.x + b.y * b.y + b.z * b.z + b.w * b.w;
#pragma unroll
  for (int off = 1; off < 64; off <<= 1) ss += __shfl_xor(ss, off);
  __shared__ float part[4];
  if ((tid & 63) == 0) part[tid >> 6] = ss;
  __syncthreads();
  float rstd = rsqrtf((part[0] + part[1] + part[2] + part[3]) * (1.0f / D_MODEL) + 1e-6f);
  const float4* g4 = (const float4*)G;
  float4 ga = g4[tid * 2], gb = g4[tid * 2 + 1];
  bf16x8 o;
  o[0] = f2b(a.x * rstd * ga.x); o[1] = f2b(a.y * rstd * ga.y);
  o[2] = f2b(a.z * rstd * ga.z); o[3] = f2b(a.w * rstd * ga.w);
  o[4] = f2b(b.x * rstd * gb.x); o[5] = f2b(b.y * rstd * gb.y);
  o[6] = f2b(b.z * rstd * gb.z); o[7] = f2b(b.w * rstd * gb.w);
  *((bf16x8*)(Out + (size_t)row * D_MODEL) + tid) = o;
}

// ================= 256x(BN) 8-phase GEMM (structure unchanged from R3) =================
template <int WN, int EPI>
__global__ __launch_bounds__(512, 2) void k_gemm2(const u16* __restrict__ A,
                                                  const u16* __restrict__ Bw,
                                                  void* __restrict__ O0,
                                                  void* __restrict__ O1,
                                                  void* __restrict__ O2,
                                                  const float* __restrict__ bias,
                                                  const float* __restrict__ res,
                                                  const u16* __restrict__ aux,
                                                  int M, int N, int K) {
  constexpr int BN = WN * 64;
  constexpr int PB = BN * 64;  // B plane bytes
  __shared__ __align__(128) char lds[65536 + 4 * PB];
  const int tid = threadIdx.x;
  const int w = tid >> 6, lane = tid & 63;
  const int lo = lane & 15, hi = lane >> 4;
  const int wr = w >> 2, wc = w & 3;

  const int ntN = N / BN;
  const int nwg = gridDim.x * gridDim.y;
  const int flat = blockIdx.y * gridDim.x + blockIdx.x;
  const int swz = (flat & 7) * (nwg >> 3) + (flat >> 3);
  const int tm = swz / ntN, tn = swz % ntN;
  const int m0 = tm * 256, n0 = tn * BN;

  auto stA = [&](int nb, int kk, int k0) {
#pragma unroll
    for (int j = 0; j < 2; ++j) {
      int row = j * 128 + (tid >> 2);
      const u16* g = A + (size_t)(m0 + row) * K + k0 + kk * 32 + (tid & 3) * 8;
      gload16(g, lds + nb * 32768 + kk * 16384 + j * 8192 + tid * 16);
    }
  };
  auto stB = [&](int nb, int kk, int k0) {
#pragma unroll
    for (int j = 0; j < WN / 2; ++j) {
      int row = j * 128 + (tid >> 2);
      const u16* g = Bw + (size_t)(n0 + row) * K + k0 + kk * 32 + (tid & 3) * 8;
      gload16(g, lds + 65536 + nb * 2 * PB + kk * PB + j * 8192 + tid * 16);
    }
  };
  auto ldA = [&](int buf, int kk, int mf) {
    return *(const bf16x8*)(lds + buf * 32768 + kk * 16384 +
                            (wr * 128 + mf * 16 + lo) * 64 + hi * 16);
  };
  auto ldB = [&](int buf, int kk, int nf) {
    return *(const bf16x8*)(lds + 65536 + buf * 2 * PB + kk * PB +
                            (wc * (WN * 16) + nf * 16 + lo) * 64 + hi * 16);
  };
#define VMCNT_CONFIRM()                                             \
  do {                                                              \
    if constexpr (WN == 4)                                          \
      asm volatile("s_waitcnt vmcnt(4)" ::: "memory");              \
    else                                                            \
      asm volatile("s_waitcnt vmcnt(3)" ::: "memory");              \
    SB0();                                                          \
  } while (0)

  f32x4 acc[8][WN];
#pragma unroll
  for (int i = 0; i < 8; i++)
#pragma unroll
    for (int j = 0; j < WN; j++) acc[i][j] = (f32x4){0.f, 0.f, 0.f, 0.f};

  stA(0, 0, 0);
  stB(0, 0, 0);
  stA(0, 1, 0);
  stB(0, 1, 0);
  VMCNT_CONFIRM();
  BARRIER();

  const int KT = K / 64;
  for (int kt = 0; kt < KT; ++kt) {
    const int buf = kt & 1, nb = buf ^ 1;
    int kn = (kt + 1) * 64;
    if (kn >= K) kn = 0;  // dummy stage on last tile (never consumed)
    bf16x8 aF[4], bF[WN];

    // ---- phase 1: kk=0, m-frags 0..3 ----
#pragma unroll
    for (int i = 0; i < 4; i++) aF[i] = ldA(buf, 0, i);
#pragma unroll
    for (int j = 0; j < WN; j++) bF[j] = ldB(buf, 0, j);
    stA(nb, 0, kn);
    BARRIER();
    LGKM0();
    __builtin_amdgcn_s_setprio(1);
#pragma unroll
    for (int i = 0; i < 4; i++)
#pragma unroll
      for (int j = 0; j < WN; j++)
        acc[i][j] = __builtin_amdgcn_mfma_f32_16x16x32_bf16(aF[i], bF[j], acc[i][j], 0, 0, 0);
    __builtin_amdgcn_s_setprio(0);
    BARRIER();

    // ---- phase 2: kk=0, m-frags 4..7 ----
#pragma unroll
    for (int i = 0; i < 4; i++) aF[i] = ldA(buf, 0, 4 + i);
    stB(nb, 0, kn);
    VMCNT_CONFIRM();
    BARRIER();
    LGKM0();
    __builtin_amdgcn_s_setprio(1);
#pragma unroll
    for (int i = 0; i < 4; i++)
#pragma unroll
      for (int j = 0; j < WN; j++)
        acc[4 + i][j] = __builtin_amdgcn_mfma_f32_16x16x32_bf16(aF[i], bF[j], acc[4 + i][j], 0, 0, 0);
    __builtin_amdgcn_s_setprio(0);
    BARRIER();

    // ---- phase 3: kk=1, m-frags 0..3 ----
#pragma unroll
    for (int i = 0; i < 4; i++) aF[i] = ldA(buf, 1, i);
#pragma unroll
    for (int j = 0; j < WN; j++) bF[j] = ldB(buf, 1, j);
    stA(nb, 1, kn);
    BARRIER();
    LGKM0();
    __builtin_amdgcn_s_setprio(1);
#pragma unroll
    for (int i = 0; i < 4; i++)
#pragma unroll
      for (int j = 0; j < WN; j++)
        acc[i][j] = __builtin_amdgcn_mfma_f32_16x16x32_bf16(aF[i], bF[j], acc[i][j], 0, 0, 0);
    __builtin_amdgcn_s_setprio(0);
    BARRIER();

    // ---- phase 4: kk=1, m-frags 4..7 ----
#pragma unroll
    for (int i = 0; i < 4; i++) aF[i] = ldA(buf, 1, 4 + i);
    stB(nb, 1, kn);
    VMCNT_CONFIRM();
    BARRIER();
    LGKM0();
    __builtin_amdgcn_s_setprio(1);
#pragma unroll
    for (int i = 0; i < 4; i++)
#pragma unroll
      for (int j = 0; j < WN; j++)
        acc[4 + i][j] = __builtin_amdgcn_mfma_f32_16x16x32_bf16(aF[i], bF[j], acc[4 + i][j], 0, 0, 0);
    __builtin_amdgcn_s_setprio(0);
    BARRIER();
  }

  // ---- epilogue ----
  u16* qkvout = nullptr;
  int c0 = 0;
  if (EPI == 1) {
    int seg = n0 >> 11;
    qkvout = (u16*)(seg == 0 ? O0 : (seg == 1 ? O1 : O2));
    c0 = n0 & 2047;
  }
#pragma unroll
  for (int i = 0; i < 8; i++) {
#pragma unroll
    for (int j = 0; j < WN; j++) {
      int colL = wc * (WN * 16) + j * 16 + lo;
#pragma unroll
      for (int r = 0; r < 4; r++) {
        int row = m0 + wr * 128 + i * 16 + hi * 4 + r;
        float v = acc[i][j][r];
        if (EPI == 0) {
          ((u16*)O0)[(size_t)row * N + n0 + colL] = f2b(v);
        } else if (EPI == 1) {
          qkvout[(size_t)row * 2048 + c0 + colL] = f2b(v);
        } else if (EPI == 2) {
          size_t idx = (size_t)row * N + n0 + colL;
          ((float*)O0)[idx] = v + bias[n0 + colL] + res[idx];
        } else if (EPI == 3) {
          size_t idx = (size_t)row * N + n0 + colL;
          ((float*)O0)[idx] = v + res[idx];
        } else {
          size_t idx = (size_t)row * N + n0 + colL;
          float v1 = b2f(aux[idx]);
          float sig = 1.f / (1.f + __expf(-v1));
          ((u16*)O0)[idx] = f2b(v1 * sig * v);
        }
      }
    }
  }
#undef VMCNT_CONFIRM
}

// ---------------- RoPE (in-place on bf16 q,k) ----------------
__global__ __launch_bounds__(256) void k_rope(u16* __restrict__ Qb, u16* __restrict__ Kb,
                                              const float* __restrict__ F) {
  int n = MTOK * (D_MODEL / 2);
  int stride = gridDim.x * 256;
  for (int t = blockIdx.x * 256 + threadIdx.x; t < n; t += stride) {
    int i = t & 63;
    int rest = t >> 6;
    int hh = rest & 15;
    int tok = rest >> 4;
    int s = tok & (SEQ - 1);
    float4 f = ((const float4*)F)[s * 64 + i];
    size_t off = (size_t)tok * D_MODEL + hh * HDIM + i * 2;
    float x0 = b2f(Qb[off]), x1 = b2f(Qb[off + 1]);
    Qb[off] = f2b(x0 * f.x + x1 * f.y);
    Qb[off + 1] = f2b(x0 * f.z + x1 * f.w);
    x0 = b2f(Kb[off]); x1 = b2f(Kb[off + 1]);
    Kb[off] = f2b(x0 * f.x + x1 * f.y);
    Kb[off + 1] = f2b(x0 * f.z + x1 * f.w);
  }
}

// ---------------- V transpose: V[4096tok][2048] -> VT[32bh][128d][2048s] ----------------
__global__ __launch_bounds__(256) void k_vt(const u16* __restrict__ V, u16* __restrict__ VT) {
  __shared__ u16 t[64][72];
  const int stile = blockIdx.x;
  const int bh = blockIdx.y;
  const int dz = blockIdx.z;
  const int b = bh >> 4, h = bh & 15;
  const int tok0 = b * SEQ + stile * 64;
  const int d0 = dz * 64;
  const int tid = threadIdx.x;
#pragma unroll
  for (int p = 0; p < 2; p++) {
    int idx = p * 256 + tid;
    int row = idx >> 3, seg = idx & 7;
    bf16x8 v = *(const bf16x8*)(V + (size_t)(tok0 + row) * D_MODEL + h * HDIM + d0 + seg * 8);
    *(bf16x8*)(&t[row][seg * 8]) = v;
  }
  __syncthreads();
#pragma unroll
  for (int p = 0; p < 2; p++) {
    int idx = p * 256 + tid;
    int dr = idx >> 3, seg = idx & 7;
    bf16x8 o;
#pragma unroll
    for (int e = 0; e < 8; e++) o[e] = t[seg * 8 + e][dr];
    *(bf16x8*)(VT + ((size_t)bh * HDIM + d0 + dr) * SEQ + stile * 64 + seg * 8) = o;
  }
}

// ---------------- flash v3: swapped-operand softmax, 128 q-rows/block, KVBLK=64 ----
// S^T = mfma(K_frag, Q_frag): lane holds S[q=lo][16 keys] in regs -> lane-local softmax.
// O^T = mfma(VT_frag, PT_frag): same col=q layout. P bounced via per-wave LDS [q][k],
// whose read pattern is identical to R4's verified aP read.
__global__ __launch_bounds__(256) void k_flash3(const u16* __restrict__ Q,
                                                const u16* __restrict__ Kb,
                                                const u16* __restrict__ VT,
                                                u16* __restrict__ O) {
  __shared__ u16 Kt[64 * 128];        // [key][d], slot^=(key&7)
  __shared__ u16 Vt[128 * 64];        // [d][k],  slot^=(d&7)
  __shared__ u16 Pl[4][2][16 * 72];   // per-wave, per-qg: [q-local 16][k 64], stride 72
  const int tid = threadIdx.x;
  const int w = tid >> 6, lane = tid & 63;
  const int lo = lane & 15, hi = lane >> 4;
  const int qt = blockIdx.x, bh = blockIdx.y;
  const int b = bh >> 4, h = bh & 15;
  const size_t qrow0 = (size_t)b * SEQ + qt * 128 + w * 32;  // wave owns 32 q-rows
  const float SC = 0.08838834764831845f * 1.4426950408889634f;  // scale * log2(e)

  // Q fragments (B-operand: lane-dim = q)
  bf16x8 aQ[2][4];
#pragma unroll
  for (int qg = 0; qg < 2; qg++)
#pragma unroll
    for (int kb = 0; kb < 4; kb++)
      aQ[qg][kb] = *(const bf16x8*)(Q + (qrow0 + qg * 16 + lo) * D_MODEL + h * HDIM + kb * 32 + hi * 8);

  float m_s[2] = {-3.0e38f, -3.0e38f}, l_s[2] = {0.f, 0.f};
  f32x4 oacc[2][8];
#pragma unroll
  for (int qg = 0; qg < 2; qg++)
#pragma unroll
    for (int d = 0; d < 8; d++) oacc[qg][d] = (f32x4){0.f, 0.f, 0.f, 0.f};

  // staging source offsets (swizzle-inverted), constant across kt
  const int krowL = tid >> 4;
  const int kslot = (tid & 15) ^ (krowL & 7);
  const int vrowL = tid >> 3;
  const int vslot = (tid & 7) ^ (vrowL & 7);
  const u16* Kbase = Kb + (size_t)b * SEQ * D_MODEL + h * HDIM;
  const u16* Vbase = VT + (size_t)bh * HDIM * SEQ;
  unsigned* Plw = (unsigned*)&Pl[w][0][0];  // u32 view, qg stride = 16*72/2 = 576

  for (int kt = 0; kt < SEQ / 64; kt++) {
    __syncthreads();
#pragma unroll
    for (int t = 0; t < 4; t++) {
      int row = t * 16 + krowL;
      const u16* g = Kbase + (size_t)(kt * 64 + row) * D_MODEL + kslot * 8;
      gload16(g, (char*)Kt + t * 4096 + tid * 16);
    }
#pragma unroll
    for (int t = 0; t < 4; t++) {
      int row = t * 32 + vrowL;
      const u16* g = Vbase + (size_t)row * SEQ + kt * 64 + vslot * 8;
      gload16(g, (char*)Vt + t * 4096 + tid * 16);
    }
    __syncthreads();

    // ---- QK^T (swapped): S^T[key][q] ----
    f32x4 sf[2][4];
#pragma unroll
    for (int cb = 0; cb < 4; cb++) {
      bf16x8 kA[4];
#pragma unroll
      for (int kb = 0; kb < 4; kb++) {
        int ps = (kb * 4 + hi) ^ (lo & 7);
        kA[kb] = *(const bf16x8*)(Kt + (cb * 16 + lo) * 128 + ps * 8);
      }
#pragma unroll
      for (int qg = 0; qg < 2; qg++) {
        f32x4 s = (f32x4){0.f, 0.f, 0.f, 0.f};
#pragma unroll
        for (int kb = 0; kb < 4; kb++)
          s = __builtin_amdgcn_mfma_f32_16x16x32_bf16(kA[kb], aQ[qg][kb], s, 0, 0, 0);
        sf[qg][cb] = s;
      }
    }

    // ---- softmax: lane-local over 16 keys + 2 wide shfls ----
    float tsc[2];
    bool ok = true;
#pragma unroll
    for (int qg = 0; qg < 2; qg++) {
      float t0 = fmaxf(fmaxf(sf[qg][0][0], sf[qg][0][1]), fmaxf(sf[qg][0][2], sf[qg][0][3]));
      float t1 = fmaxf(fmaxf(sf[qg][1][0], sf[qg][1][1]), fmaxf(sf[qg][1][2], sf[qg][1][3]));
      float t2 = fmaxf(fmaxf(sf[qg][2][0], sf[qg][2][1]), fmaxf(sf[qg][2][2], sf[qg][2][3]));
      float t3 = fmaxf(fmaxf(sf[qg][3][0], sf[qg][3][1]), fmaxf(sf[qg][3][2], sf[qg][3][3]));
      float t = fmaxf(fmaxf(t0, t1), fmaxf(t2, t3));
      t = fmaxf(t, __shfl_xor(t, 16));
      t = fmaxf(t, __shfl_xor(t, 32));
      tsc[qg] = t * SC;
      ok = ok && (tsc[qg] - m_s[qg] <= 11.5f);
    }
    bool skip = __all(ok);
#pragma unroll
    for (int qg = 0; qg < 2; qg++) {
      float mm = m_s[qg];
      if (!skip) {
        mm = fmaxf(m_s[qg], tsc[qg]);
        float alpha = exp2f(m_s[qg] - mm);
        l_s[qg] *= alpha;
#pragma unroll
        for (int d = 0; d < 8; d++) oacc[qg][d] *= alpha;
        m_s[qg] = mm;
      }
      float rs = 0.f;
#pragma unroll
      for (int cb = 0; cb < 4; cb++) {
        float p0 = exp2f(sf[qg][cb][0] * SC - mm);
        float p1 = exp2f(sf[qg][cb][1] * SC - mm);
        float p2 = exp2f(sf[qg][cb][2] * SC - mm);
        float p3 = exp2f(sf[qg][cb][3] * SC - mm);
        rs += (p0 + p1) + (p2 + p3);
        unsigned pk0, pk1;
        asm("v_cvt_pk_bf16_f32 %0, %1, %2" : "=v"(pk0) : "v"(p0), "v"(p1));
        asm("v_cvt_pk_bf16_f32 %0, %1, %2" : "=v"(pk1) : "v"(p2), "v"(p3));
        Plw[qg * 576 + lo * 36 + cb * 8 + hi * 2 + 0] = pk0;
        Plw[qg * 576 + lo * 36 + cb * 8 + hi * 2 + 1] = pk1;
      }
      rs += __shfl_xor(rs, 16);
      rs += __shfl_xor(rs, 32);
      l_s[qg] += rs;
    }
    LGKM0();

    // ---- PV (swapped): O^T[d][q] ----
    bf16x8 aP[2][2];
#pragma unroll
    for (int qg = 0; qg < 2; qg++)
#pragma unroll
      for (int ks = 0; ks < 2; ks++)
        aP[qg][ks] = *(const bf16x8*)(&Pl[w][qg][lo * 72 + ks * 32 + hi * 8]);
#pragma unroll
    for (int db = 0; db < 8; db++) {
      bf16x8 vA[2];
#pragma unroll
      for (int ks = 0; ks < 2; ks++) {
        int ps = (ks * 4 + hi) ^ (lo & 7);
        vA[ks] = *(const bf16x8*)(Vt + (db * 16 + lo) * 64 + ps * 8);
      }
#pragma unroll
      for (int qg = 0; qg < 2; qg++)
#pragma unroll
        for (int ks = 0; ks < 2; ks++)
          oacc[qg][db] = __builtin_amdgcn_mfma_f32_16x16x32_bf16(vA[ks], aP[qg][ks], oacc[qg][db], 0, 0, 0);
    }
  }

  // ---- epilogue: O^T[d][q] -> O[q][d], 8B packed stores ----
#pragma unroll
  for (int qg = 0; qg < 2; qg++) {
    float inv = 1.f / l_s[qg];
    size_t rowoff = (qrow0 + qg * 16 + lo) * D_MODEL + h * HDIM;
#pragma unroll
    for (int db = 0; db < 8; db++) {
      s16x4 o;
#pragma unroll
      for (int r = 0; r < 4; r++) o[r] = (short)f2b(oacc[qg][db][r] * inv);
      *(s16x4*)(O + rowoff + db * 16 + hi * 4) = o;
    }
  }
}

extern "C" void kernel_launch(void* const* d_in, const int* in_sizes, int n_in,
                              void* d_out, int out_size, void* d_ws, size_t ws_size,
                              hipStream_t stream) {
  (void)in_sizes; (void)n_in; (void)out_size; (void)ws_size;
  const float* x  = (const float*)d_in[0];
  const float* fc = (const float*)d_in[1];
  const float* wq = (const float*)d_in[2];
  const float* wk = (const float*)d_in[3];
  const float* wv = (const float*)d_in[4];
  const float* wo = (const float*)d_in[5];
  const float* bo = (const float*)d_in[6];
  const float* w1 = (const float*)d_in[7];
  const float* w3 = (const float*)d_in[8];
  const float* w2 = (const float*)d_in[9];
  const float* ga = (const float*)d_in[10];
  const float* gf = (const float*)d_in[11];
  float* out = (float*)d_out;  // also holds hres (fp32) between sublayers

  // ---- workspace (~139 MB) ----
  char* p = (char*)d_ws;
  auto alloc = [&](size_t bytes) { char* r = p; p += (bytes + 255) & ~(size_t)255; return r; };
  u16* xn  = (u16*)alloc((size_t)MTOK * D_MODEL * 2);  // reused as vbt after QKV GEMM
  u16* qb  = (u16*)alloc((size_t)MTOK * D_MODEL * 2);  // reused as hn after flash
  u16* kb  = (u16*)alloc((size_t)MTOK * D_MODEL * 2);
  u16* vb  = (u16*)alloc((size_t)MTOK * D_MODEL * 2);  // reused as ob after k_vt
  u16* x1  = (u16*)alloc((size_t)MTOK * HP2 * 2);
  u16* wsl = (u16*)alloc((size_t)3 * D_MODEL * D_MODEL * 2);  // shared weight slot
  u16* vbt = xn;
  u16* ob  = vb;
  u16* hn  = qb;

  // ---- attention sublayer ----
  k_rmsnorm<<<MTOK, 256, 0, stream>>>(x, ga, xn);
  k_conv3<<<1536, 256, 0, stream>>>(wq, wk, wv, wsl);
  k_gemm2<2, 1><<<dim3(6144 / 128, MTOK / 256), 512, 0, stream>>>(
      xn, wsl, qb, kb, vb, nullptr, nullptr, nullptr, MTOK, 6144, D_MODEL);
  k_rope<<<1024, 256, 0, stream>>>(qb, kb, fc);
  k_vt<<<dim3(SEQ / 64, BATCH * NHEADS, 2), 256, 0, stream>>>(vb, vbt);
  dim3 gfl(SEQ / 128, BATCH * NHEADS);
  k_flash3<<<gfl, 256, 0, stream>>>(qb, kb, vbt, ob);  // ob overwrites vb (dead after k_vt)
  k_conv8<<<1024, 256, 0, stream>>>(wo, wsl, D_MODEL * D_MODEL / 8);
  k_gemm2<2, 2><<<dim3(2048 / 128, MTOK / 256), 512, 0, stream>>>(
      ob, wsl, out, nullptr, nullptr, bo, x, nullptr, MTOK, D_MODEL, D_MODEL);

  // ---- FFN sublayer (hres lives in `out`) ----
  k_rmsnorm<<<MTOK, 256, 0, stream>>>(out, gf, hn);
  k_convpad<<<1024, 256, 0, stream>>>(w1, wsl, HIDDEN_, D_MODEL, HP2, D_MODEL);
  k_gemm2<2, 0><<<dim3(HP2 / 128, MTOK / 256), 512, 0, stream>>>(
      hn, wsl, x1, nullptr, nullptr, nullptr, nullptr, nullptr, MTOK, HP2, D_MODEL);
  k_convpad<<<1024, 256, 0, stream>>>(w3, wsl, HIDDEN_, D_MODEL, HP2, D_MODEL);
  k_gemm2<2, 4><<<dim3(HP2 / 128, MTOK / 256), 512, 0, stream>>>(
      hn, wsl, x1, nullptr, nullptr, nullptr, nullptr, x1, MTOK, HP2, D_MODEL);
  k_convpad<<<1024, 256, 0, stream>>>(w2, wsl, D_MODEL, HIDDEN_, D_MODEL, HP2);
  k_gemm2<2, 3><<<dim3(2048 / 128, MTOK / 256), 512, 0, stream>>>(
      x1, wsl, out, nullptr, nullptr, nullptr, out, nullptr, MTOK, D_MODEL, HP2);
}